// Round 13
// baseline (254.336 us; speedup 1.0000x reference)
//
#include <hip/hip_runtime.h>
#include <hip/hip_bf16.h>
#include <math.h>

// Problem dims (fixed by reference)
#define BB 64
#define SS 200
#define TT 32
#define EE 128
#define CC 128
#define HH 100
#define G3 300           // 3*H
#define OUTD 104
#define NTREE (BB*SS)    // 12800

typedef __attribute__((ext_vector_type(4))) float f32x4;
typedef _Float16 f16x8 __attribute__((ext_vector_type(8)));

__device__ inline float fast_sigmoid(float x) {
    return __builtin_amdgcn_rcpf(1.f + __builtin_amdgcn_exp2f(-1.4426950408889634f * x));
}
__device__ inline float fast_tanh(float x) {
    return 1.f - 2.f * __builtin_amdgcn_rcpf(1.f + __builtin_amdgcn_exp2f(2.8853900817779268f * x));
}
__device__ inline unsigned pack2f16(float a, float b) {
    union { _Float16 h[2]; unsigned u; } x;
    x.h[0] = (_Float16)a; x.h[1] = (_Float16)b;
    return x.u;
}
__device__ inline unsigned f2u(float v) { union { float f; unsigned u; } x; x.f = v; return x.u; }
__device__ inline float u2f(unsigned v) { union { unsigned u; float f; } x; x.u = v; return x.f; }
// subtree size of node p in the 32-node complete binary tree
__device__ inline float subtree_cnt(int p) {
    return (p == 0) ? 32.f : (p == 1) ? 16.f : (p == 2) ? 15.f :
           (p == 3) ? 8.f  : (p <= 6) ? 7.f  : (p == 7) ? 4.f  :
           (p <= 14) ? 3.f : (p == 15) ? 2.f : 1.f;
}

// LDS-only barrier: waits ds-ops (lgkmcnt) but does NOT drain vmcnt, so in-flight
// global prefetch loads stay outstanding across the barrier (waited at use).
#define BAR() asm volatile("s_waitcnt lgkmcnt(0)\n\ts_barrier" ::: "memory")

// Workspace layout (bytes), total ~30.9 MB:
//   wl    @ 0        : 32768    (k1 W_lin fragment image, fp16)
//   k2b   @ 32768    : 163840   (W_ih fragment image, fp16; consumed by fused k1)
//   lf    @ 196608   : 2048     (k1 L-matrix fragment image, fp16)
//   gx    @ 198656   : 30720000 (fp32)
//   pool  @ 0        : 51200    -- aliases wl/k2b/lf; k3 writes AFTER k1 read them.

// ---------------- K0: weight/L fragment images (11 blocks; idempotent)
__global__ __launch_bounds__(256) void k0_prep(const float* __restrict__ w_lin,
                                               const float* __restrict__ w_ih_f,
                                               const float* __restrict__ w_ih_b,
                                               _Float16* __restrict__ wl,
                                               _Float16* __restrict__ k2b,
                                               _Float16* __restrict__ lf) {
    const int tid  = threadIdx.x;
    const int wave = tid >> 6;
    const int lane = tid & 63;
    const int r = lane & 15;
    const int q = lane >> 4;
    if (blockIdx.x == 0) {
        // k1 image: flat idx (w8 = wave*2+nt, kt, lane) -> W_lin[n=w8*16+r][k=kt*32+q*8 ..+8]
#pragma unroll
        for (int nt = 0; nt < 2; ++nt)
#pragma unroll
            for (int kt = 0; kt < 4; ++kt) {
                const int n = wave * 32 + nt * 16 + r;
                const float* src = w_lin + (long)n * EE + kt * 32 + q * 8;
                f16x8 f;
#pragma unroll
                for (int e = 0; e < 8; ++e) f[e] = (_Float16)src[e];
                *(f16x8*)&wl[(size_t)((((wave * 2 + nt) * 4 + kt) * 64) + lane) * 8] = f;
            }
        // L-matrix A-fragments (wave 0 only): L[p][n] = (n in subtree(p))
        if (wave == 0) {
#pragma unroll
            for (int mt2 = 0; mt2 < 2; ++mt2) {
                const int p = mt2 * 16 + r;
                f16x8 f;
#pragma unroll
                for (int e = 0; e < 8; ++e) {
                    int x = q * 8 + e;
                    while (x > p) x = (x - 1) >> 1;
                    f[e] = (_Float16)((x == p) ? 1.f : 0.f);
                }
                *(f16x8*)&lf[(size_t)(mt2 * 64 + lane) * 8] = f;
            }
        }
    } else {
        // W_ih image: 16-col tile T = (nb*4+wave) in 0..39, kt, lane
        const int nb = blockIdx.x - 1;           // 0..9
        const int n = nb * 64 + wave * 16 + r;   // padded col 0..639
        const int dir = (n >= 320) ? 1 : 0;
        const int j = n - dir * 320;
        const int jj = (j < G3) ? j : 0;         // pad rows clamped (results discarded)
        const float* w = dir ? w_ih_b : w_ih_f;
#pragma unroll
        for (int kt = 0; kt < 4; ++kt) {
            const float* src = w + (long)jj * EE + kt * 32 + q * 8;
            f16x8 f;
#pragma unroll
            for (int e = 0; e < 8; ++e) f[e] = (_Float16)src[e];
            *(f16x8*)&k2b[(size_t)((((nb * 4 + wave) * 4 + kt) * 64) + lane) * 8] = f;
        }
    }
}

// ---------------- K1 (fused k1+k2): 4 trees/block (3200 blocks, 512 threads).
// embed-gather(fp32->fp16) -> MFMA1 (c = W_lin.e) -> wave-local bpermute ->
// MFMA2 (h = L.c, subtree sums) -> max epilogue -> x_sh[4 trees][128] ->
// inline k2 GEMM (gx = x @ W_ih^T + b_ih) -> gx. No thi round-trip, no k2 dispatch.
#define K1_TPB 4
#define K1_ROWS (K1_TPB * TT)    // 128
#define LDA 136                  // fp16/row: 128 + 8 pad
__global__ __launch_bounds__(512, 4) void k1_fused(const int* __restrict__ tok,
                                                   const float* __restrict__ emb,
                                                   const _Float16* __restrict__ wl,
                                                   const _Float16* __restrict__ k2b,
                                                   const _Float16* __restrict__ lf,
                                                   const float* __restrict__ b_lin,
                                                   const float* __restrict__ b_ih_f,
                                                   const float* __restrict__ b_ih_b,
                                                   float* __restrict__ gx) {
    __shared__ __align__(16) _Float16 A_sh[K1_ROWS * LDA];   // 34816 B
    __shared__ __align__(16) _Float16 x_sh[16 * LDA];        // 4352 B (rows 4..15 zero)
    __shared__ int tok_sh[K1_ROWS];

    const int tid  = threadIdx.x;
    const int wave = tid >> 6;      // 0..7, owns cols [16w, 16w+16) of MFMA1
    const int lane = tid & 63;
    const int r = lane & 15;
    const int q = lane >> 4;

    // ---- B fragments (W_lin) + L fragments from prebuilt images (coalesced 16B loads)
    f16x8 bfrag[4];
#pragma unroll
    for (int kt = 0; kt < 4; ++kt)
        bfrag[kt] = *(const f16x8*)&wl[(size_t)(((wave * 4 + kt) * 64) + lane) * 8];
    f16x8 l2f[2];
#pragma unroll
    for (int mt2 = 0; mt2 < 2; ++mt2)
        l2f[mt2] = *(const f16x8*)&lf[(size_t)(mt2 * 64 + lane) * 8];
    const float bias = b_lin[wave * 16 + r];

    const int tree0 = blockIdx.x * K1_TPB;
    if (tid < K1_ROWS) tok_sh[tid] = tok[tree0 * TT + tid];
    // zero x_sh (rows 4..15 stay zero; rows 0..3 overwritten later, ordered by barriers)
    for (int i = tid; i < 16 * LDA; i += 512) x_sh[i] = (_Float16)0.f;
    __syncthreads();

    // ---- gather fp32 embeddings -> fp16 LDS (16 lanes cover one 128-float row)
#pragma unroll
    for (int i = 0; i < 4; ++i) {
        const int idx = tid + i * 512;          // 0..2047
        const int row = idx >> 4;               // node row 0..127
        const int p4  = idx & 15;               // 8-float chunk
        const float4* src = (const float4*)(emb + (long)tok_sh[row] * EE + p4 * 8);
        const float4 e0 = src[0], e1 = src[1];
        f16x8 v;
        v[0] = (_Float16)e0.x; v[1] = (_Float16)e0.y; v[2] = (_Float16)e0.z; v[3] = (_Float16)e0.w;
        v[4] = (_Float16)e1.x; v[5] = (_Float16)e1.y; v[6] = (_Float16)e1.z; v[7] = (_Float16)e1.w;
        *(f16x8*)&A_sh[row * LDA + p4 * 8] = v;
    }
    __syncthreads();

    // ---- MFMA1: C1[128 nodes][16 cols] per wave; pack each m-tile to fp16 pairs
    unsigned pk[8][2];    // pk[mt][pair]: pair0 = regs(0,1), pair1 = regs(2,3)
#pragma unroll
    for (int mt = 0; mt < 8; ++mt) {
        const int m = mt * 16 + r;
        f32x4 acc = (f32x4)(0.f);
#pragma unroll
        for (int kt = 0; kt < 4; ++kt) {
            f16x8 af = *(const f16x8*)&A_sh[m * LDA + kt * 32 + q * 8];
            acc = __builtin_amdgcn_mfma_f32_16x16x32_f16(af, bfrag[kt], acc, 0, 0, 0);
        }
        pk[mt][0] = pack2f16(acc[0], acc[1]);
        pk[mt][1] = pack2f16(acc[2], acc[3]);
    }

    // ---- per tree: wave-local bpermute (both-tile fetch + dest-side select; the
    // bpermute src operand is evaluated on the SOURCE lane) -> MFMA2 -> max -> x_sh
    const int l0 = (r + 16 * ((2 * q) & 3)) << 2;
    const int l1 = (r + 16 * ((2 * q + 1) & 3)) << 2;
    const bool hi = (q >> 1) != 0;
#pragma unroll
    for (int t = 0; t < K1_TPB; ++t) {
        const unsigned x0 = __builtin_amdgcn_ds_bpermute(l0, (int)pk[2 * t][0]);
        const unsigned y0 = __builtin_amdgcn_ds_bpermute(l0, (int)pk[2 * t + 1][0]);
        const unsigned x1 = __builtin_amdgcn_ds_bpermute(l0, (int)pk[2 * t][1]);
        const unsigned y1 = __builtin_amdgcn_ds_bpermute(l0, (int)pk[2 * t + 1][1]);
        const unsigned x2 = __builtin_amdgcn_ds_bpermute(l1, (int)pk[2 * t][0]);
        const unsigned y2 = __builtin_amdgcn_ds_bpermute(l1, (int)pk[2 * t + 1][0]);
        const unsigned x3 = __builtin_amdgcn_ds_bpermute(l1, (int)pk[2 * t][1]);
        const unsigned y3 = __builtin_amdgcn_ds_bpermute(l1, (int)pk[2 * t + 1][1]);
        union { unsigned u[4]; f16x8 v; } b2;
        b2.u[0] = hi ? y0 : x0;
        b2.u[1] = hi ? y1 : x1;
        b2.u[2] = hi ? y2 : x2;
        b2.u[3] = hi ? y3 : x3;

        float mx = -1e30f;
#pragma unroll
        for (int mt2 = 0; mt2 < 2; ++mt2) {
            f32x4 a2 = __builtin_amdgcn_mfma_f32_16x16x32_f16(l2f[mt2], b2.v, (f32x4)(0.f), 0, 0, 0);
#pragma unroll
            for (int reg = 0; reg < 4; ++reg) {
                const int p = mt2 * 16 + q * 4 + reg;       // h(p) = C2 + cnt(p)*bias
                mx = fmaxf(mx, a2[reg] + subtree_cnt(p) * bias);
            }
        }
        mx = fmaxf(mx, __shfl_xor(mx, 16, 64));
        mx = fmaxf(mx, __shfl_xor(mx, 32, 64));
        if (q == 0)
            x_sh[t * LDA + wave * 16 + r] = (_Float16)mx;   // tree t, col wave*16+r
    }
    __syncthreads();

    // ---- inline k2 GEMM: gx[dir][tree][300] = x @ W_ih^T + b_ih.
    // A rows = trees (rows 0..3 valid, 4..15 zero); 40 n-tiles over 8 waves.
    f16x8 a2f[4];
#pragma unroll
    for (int kt = 0; kt < 4; ++kt)
        a2f[kt] = *(const f16x8*)&x_sh[r * LDA + kt * 32 + q * 8];

#pragma unroll
    for (int i = 0; i < 5; ++i) {
        const int ntg = wave * 5 + i;            // 16-col tile 0..39
        f32x4 acc = (f32x4)(0.f);
#pragma unroll
        for (int kt = 0; kt < 4; ++kt) {
            const f16x8 bh = *(const f16x8*)&k2b[(size_t)(((ntg * 4 + kt) * 64) + lane) * 8];
            acc = __builtin_amdgcn_mfma_f32_16x16x32_f16(a2f[kt], bh, acc, 0, 0, 0);
        }
        const int ng  = ntg * 16 + r;            // padded col 0..639
        const int dir = (ng >= 320) ? 1 : 0;
        const int j   = ng - dir * 320;
        if (q == 0 && j < G3) {                  // C rows q*4+reg: q==0 -> reg = tree
            const float bih = dir ? b_ih_b[j] : b_ih_f[j];
            float* gxd = gx + (long)dir * NTREE * G3;
#pragma unroll
            for (int reg = 0; reg < 4; ++reg)
                gxd[(long)(tree0 + reg) * G3 + j] = acc[reg] + bih;
        }
    }
}

// ---------------- K3 v6 (unchanged, measured 95-99 us): 1 chain/block, fp16 MFMA matvec,
// bpermute gate redistribution, one lgkm-only barrier/step, h double-buffered.
__global__ __launch_bounds__(256, 1) void k3_gru(const float* __restrict__ gx,
                                                 const float* __restrict__ w_hh_f,
                                                 const float* __restrict__ b_hh_f,
                                                 const float* __restrict__ w_hh_b,
                                                 const float* __restrict__ b_hh_b,
                                                 float* __restrict__ pool) {
    const int bid = blockIdx.x;   // 0..127
    const int dir = bid & 1;
    const int b = bid >> 1;
    const float* w_hh = dir ? w_hh_b : w_hh_f;
    const float* b_hh = dir ? b_hh_b : b_hh_f;

    __shared__ __align__(16) _Float16 h_sh[2][128];   // double-buffered h (k-pad 0)

    const int tid  = threadIdx.x;
    const int wave = tid >> 6;
    const int lane = tid & 63;
    const int r = lane & 15;
    const int q = lane >> 4;

    f16x8 bf[5][4];
#pragma unroll
    for (int i = 0; i < 5; ++i) {
        const int l = i * 16 + r;
        const int gate = l / 25;
        const int ch   = l - gate * 25;
        const bool nv  = (l < 75);
        const int row  = gate * HH + wave * 25 + ch;
#pragma unroll
        for (int kt = 0; kt < 4; ++kt) {
            f16x8 f;
#pragma unroll
            for (int e = 0; e < 8; ++e) {
                const int k = kt * 32 + q * 8 + e;
                f[e] = (_Float16)((nv && k < HH) ? w_hh[row * HH + k] : 0.f);
            }
            bf[i][kt] = f;
        }
    }

    const int m = lane;              // activation lane: m<25 owns channel c = 25w+m
    const int c = wave * 25 + m;
    const bool act = (m < 25);
    float br = 0.f, bz = 0.f, bn = 0.f;
    if (act) { br = b_hh[c]; bz = b_hh[HH + c]; bn = b_hh[2 * HH + c]; }

    if (tid < 128) { h_sh[0][tid] = (_Float16)0.f; h_sh[1][tid] = (_Float16)0.f; }

    const float* gxd = gx + (long)dir * NTREE * G3;
    const int sstep = dir ? -1 : 1;
    int s = dir ? (SS - 1) : 0;
    float xr = 0.f, xz = 0.f, xn = 0.f;
    if (act) {
        const float* row0 = gxd + ((long)b * SS + s) * G3;
        xr = row0[c]; xz = row0[HH + c]; xn = row0[2 * HH + c];
    }
    float hj = 0.f, hmax = -1e30f;
    const int lz = ((25 + m) & 15) << 2;
    const int ln = ((50 + m) & 15) << 2;
    __syncthreads();

    for (int t = 0; t < SS; ++t) {
        const int p = t & 1;
        const int s_n = s + sstep;
        float xrn = 0.f, xzn = 0.f, xnn = 0.f;
        if (act && t < SS - 1) {
            const float* row0 = gxd + ((long)b * SS + s_n) * G3;
            xrn = row0[c]; xzn = row0[HH + c]; xnn = row0[2 * HH + c];
        }

        f16x8 a[4];
#pragma unroll
        for (int kt = 0; kt < 4; ++kt)
            a[kt] = *(const f16x8*)&h_sh[p][kt * 32 + q * 8];   // broadcast b128
        float g[5];
#pragma unroll
        for (int i = 0; i < 5; ++i) {
            f32x4 a0 = __builtin_amdgcn_mfma_f32_16x16x32_f16(a[0], bf[i][0], (f32x4)(0.f), 0, 0, 0);
            a0       = __builtin_amdgcn_mfma_f32_16x16x32_f16(a[1], bf[i][1], a0, 0, 0, 0);
            f32x4 a1 = __builtin_amdgcn_mfma_f32_16x16x32_f16(a[2], bf[i][2], (f32x4)(0.f), 0, 0, 0);
            a1       = __builtin_amdgcn_mfma_f32_16x16x32_f16(a[3], bf[i][3], a1, 0, 0, 0);
            g[i] = a0[0] + a1[0];
        }

        const unsigned bz1 = __builtin_amdgcn_ds_bpermute(lz, (int)f2u(g[1]));
        const unsigned bz2 = __builtin_amdgcn_ds_bpermute(lz, (int)f2u(g[2]));
        const unsigned bz3 = __builtin_amdgcn_ds_bpermute(lz, (int)f2u(g[3]));
        const unsigned bn3 = __builtin_amdgcn_ds_bpermute(ln, (int)f2u(g[3]));
        const unsigned bn4 = __builtin_amdgcn_ds_bpermute(ln, (int)f2u(g[4]));

        if (act) {
            const float ghr = (m < 16) ? g[0] : g[1];
            const float ghz = (m < 7) ? u2f(bz1) : (m < 23) ? u2f(bz2) : u2f(bz3);
            const float ghn = (m < 14) ? u2f(bn3) : u2f(bn4);
            const float rg = fast_sigmoid(xr + ghr + br);
            const float zg = fast_sigmoid(xz + ghz + bz);
            const float ng = fast_tanh(xn + rg * (ghn + bn));
            hj = (1.f - zg) * ng + zg * hj;
            hmax = fmaxf(hmax, hj);
            h_sh[1 - p][c] = (_Float16)hj;
            xr = xrn; xz = xzn; xn = xnn;
        }
        BAR();
        s = s_n;
    }
    if (act) pool[(long)b * (2 * HH) + dir * HH + c] = hmax;
}

// ---------------- K4: out[b][o] = fc_b[o] + pool[b,:] . fc_w[o,:]
__global__ __launch_bounds__(256) void k4_fc(const float* __restrict__ pool,
                                             const float* __restrict__ fc_w,
                                             const float* __restrict__ fc_b,
                                             float* __restrict__ out) {
    const int b = blockIdx.x;
    __shared__ __align__(16) float p_sh[2 * HH];
    const int t = threadIdx.x;
    if (t < 2 * HH) p_sh[t] = pool[(long)b * (2 * HH) + t];
    __syncthreads();
    if (t < OUTD) {
        const float4* wr4 = (const float4*)(fc_w + (long)t * (2 * HH));
        const float4* p4 = (const float4*)p_sh;
        float a0 = 0.f, a1 = 0.f;
#pragma unroll
        for (int k = 0; k < 50; k += 2) {
            float4 w0 = wr4[k],   p0 = p4[k];
            float4 w1 = wr4[k+1], p1 = p4[k+1];
            a0 += w0.x*p0.x + w0.y*p0.y + w0.z*p0.z + w0.w*p0.w;
            a1 += w1.x*p1.x + w1.y*p1.y + w1.z*p1.z + w1.w*p1.w;
        }
        out[(long)b * OUTD + t] = fc_b[t] + a0 + a1;
    }
}

extern "C" void kernel_launch(void* const* d_in, const int* in_sizes, int n_in,
                              void* d_out, int out_size, void* d_ws, size_t ws_size,
                              hipStream_t stream) {
    const int*   tok    = (const int*)d_in[0];
    const float* emb    = (const float*)d_in[4];
    const float* w_lin  = (const float*)d_in[5];
    const float* b_lin  = (const float*)d_in[6];
    const float* w_ih_f = (const float*)d_in[7];
    const float* w_hh_f = (const float*)d_in[8];
    const float* b_ih_f = (const float*)d_in[9];
    const float* b_hh_f = (const float*)d_in[10];
    const float* w_ih_b = (const float*)d_in[11];
    const float* w_hh_b = (const float*)d_in[12];
    const float* b_ih_b = (const float*)d_in[13];
    const float* b_hh_b = (const float*)d_in[14];
    const float* fc_w   = (const float*)d_in[15];
    const float* fc_b   = (const float*)d_in[16];

    char* wsb = (char*)d_ws;
    _Float16* wl   = (_Float16*)(wsb);             // 32768 B
    _Float16* k2b  = (_Float16*)(wsb + 32768);     // 163840 B
    _Float16* lf   = (_Float16*)(wsb + 196608);    // 2048 B
    float*    gx   = (float*)(wsb + 198656);       // 30720000 B
    float*    pool = (float*)(wsb);                // aliases wl/k2b/lf: k3 runs after k1
    float*    out  = (float*)d_out;

    k0_prep<<<11, 256, 0, stream>>>(w_lin, w_ih_f, w_ih_b, wl, k2b, lf);
    k1_fused<<<NTREE / K1_TPB, 512, 0, stream>>>(tok, emb, wl, k2b, lf, b_lin,
                                                 b_ih_f, b_ih_b, gx);
    k3_gru <<<2 * BB, 256, 0, stream>>>(gx, w_hh_f, b_hh_f, w_hh_b, b_hh_b, pool);
    k4_fc  <<<BB, 256, 0, stream>>>(pool, fc_w, fc_b, out);
}